// Round 7
// baseline (362.310 us; speedup 1.0000x reference)
//
#include <hip/hip_runtime.h>

namespace {
constexpr int kB = 2;
constexpr int kH = 352;
constexpr int kW = 1216;
constexpr int kHW = kH * kW;        // 428032
constexpr int kN = kB * kHW;        // 856064
constexpr float kDmax = 80.0f;
constexpr float kEps = 1e-6f;
constexpr int kBlock = 256;
}

typedef _Float16 half_t;
typedef __attribute__((ext_vector_type(4))) _Float16 half4;

// Module-owned workspace, fully rewritten from inputs on every launch.
__device__ half_t g_Wh[(size_t)48 * kN];  // merged weights, fp16, ch-major (~82 MB, L3-resident)
__device__ float  g_Q[kN];                // fp32 constant term
__device__ float  g_ping[kN];             // Dt ping buffer

__device__ __forceinline__ float4 ld4(const float* p) { return *(const float4*)p; }
__device__ __forceinline__ float4 f4add(float4 a, float4 b) {
    return make_float4(a.x + b.x, a.y + b.y, a.z + b.z, a.w + b.w);
}
__device__ __forceinline__ float4 f4mul(float4 a, float4 b) {
    return make_float4(a.x * b.x, a.y * b.y, a.z * b.z, a.w * b.w);
}
__device__ __forceinline__ float4 f4fma(float4 a, float4 b, float4 c) {
    return make_float4(fmaf(a.x, b.x, c.x), fmaf(a.y, b.y, c.y),
                       fmaf(a.z, b.z, c.z), fmaf(a.w, b.w, c.w));
}
__device__ __forceinline__ float4 f4abs(float4 a) {
    return make_float4(fabsf(a.x), fabsf(a.y), fabsf(a.z), fabsf(a.w));
}
__device__ __forceinline__ float4 f4max(float4 a, float4 b) {
    return make_float4(fmaxf(a.x, b.x), fmaxf(a.y, b.y),
                       fmaxf(a.z, b.z), fmaxf(a.w, b.w));
}

// Merged-weight precompute, 4 pixels/thread, two passes.
// Rounds 2-6 invariant: ~35-46 cycles per VMEM instruction per CU regardless
// of structure (reg loads, async DMA, any occupancy). Prep's instructions were
// all 4 B/lane -> pinned at ~2 TB/s; step's are 16 B/lane -> ~6.9 TB/s. Fix:
// every prep load is float4 (16 B/lane, 1 KB/wave). Pass 1 streams channels
// through 8-deep chunked loads into abs-sum accumulators (values die
// immediately -> no 83-float live set). Pass 2 re-walks the 49 offsets
// re-loading channels; reuse distance ~80 MB << 256 MB L3 -> L3 hits.
__global__ __launch_bounds__(kBlock, 2) void prep_kernel(
    const float* __restrict__ D0, const float* __restrict__ DL,
    const float* __restrict__ ML, const float* __restrict__ A3,
    const float* __restrict__ A5, const float* __restrict__ A7,
    const float* __restrict__ SG, const float* __restrict__ AL)
{
    int t = blockIdx.x * kBlock + threadIdx.x;   // 0 .. kN/4-1
    int p = t * 4;
    int b = p / kHW;                             // kHW % 4 == 0
    int rem = p - b * kHW;

    const float* a3p = A3 + (size_t)b * 9 * kHW + rem;
    const float* a5p = A5 + (size_t)b * 25 * kHW + rem;
    const float* a7p = A7 + (size_t)b * 49 * kHW + rem;
    const float* sgp = SG + (size_t)b * 3 * kHW + rem;

    // Small per-pixel inputs (7 float4 loads).
    float4 g0 = ld4(sgp);
    float4 g1 = ld4(sgp + kHW);
    float4 g2 = ld4(sgp + 2 * kHW);
    float4 d0 = ld4(D0 + p);
    float4 dl = ld4(DL + p);
    float4 ml = ld4(ML + p);
    float4 alv = ld4(AL + p);

    // ---- Pass 1: |.|-sums via 8-deep chunked float4 loads ----
    float4 zero = make_float4(0.f, 0.f, 0.f, 0.f);
    float4 s7v = zero, s5v = zero, s3v = zero;
    float4 c7v = zero, c5v = zero, c3v = zero;
    float4 buf[8];

#pragma unroll
    for (int ch = 0; ch < 6; ++ch) {             // a7: 48 of 49
#pragma unroll
        for (int j = 0; j < 8; ++j) buf[j] = ld4(a7p + (size_t)(ch * 8 + j) * kHW);
#pragma unroll
        for (int j = 0; j < 8; ++j) {
            if (ch * 8 + j == 24) c7v = buf[j];
            s7v = f4add(s7v, f4abs(buf[j]));
        }
    }
    buf[0] = ld4(a7p + (size_t)48 * kHW);
    s7v = f4add(s7v, f4abs(buf[0]));

#pragma unroll
    for (int ch = 0; ch < 3; ++ch) {             // a5: 24 of 25
#pragma unroll
        for (int j = 0; j < 8; ++j) buf[j] = ld4(a5p + (size_t)(ch * 8 + j) * kHW);
#pragma unroll
        for (int j = 0; j < 8; ++j) {
            if (ch * 8 + j == 12) c5v = buf[j];
            s5v = f4add(s5v, f4abs(buf[j]));
        }
    }
    buf[0] = ld4(a5p + (size_t)24 * kHW);
    s5v = f4add(s5v, f4abs(buf[0]));

#pragma unroll
    for (int j = 0; j < 8; ++j) buf[j] = ld4(a3p + (size_t)j * kHW);   // a3: 8 of 9
#pragma unroll
    for (int j = 0; j < 8; ++j) {
        if (j == 4) c3v = buf[j];
        s3v = f4add(s3v, f4abs(buf[j]));
    }
    buf[0] = ld4(a3p + (size_t)8 * kHW);
    s3v = f4add(s3v, f4abs(buf[0]));

    // ---- Per-pixel scalars: softmax, mask/alpha blend, merged scales ----
    float4 mx = f4max(g0, f4max(g1, g2));
    float4 e0 = make_float4(expf(g0.x - mx.x), expf(g0.y - mx.y), expf(g0.z - mx.z), expf(g0.w - mx.w));
    float4 e1 = make_float4(expf(g1.x - mx.x), expf(g1.y - mx.y), expf(g1.z - mx.z), expf(g1.w - mx.w));
    float4 e2 = make_float4(expf(g2.x - mx.x), expf(g2.y - mx.y), expf(g2.z - mx.z), expf(g2.w - mx.w));
    float4 einv = make_float4(1.f / (e0.x + e1.x + e2.x), 1.f / (e0.y + e1.y + e2.y),
                              1.f / (e0.z + e1.z + e2.z), 1.f / (e0.w + e1.w + e2.w));

    float4 al = f4max(zero, f4max(make_float4(-1e30f,-1e30f,-1e30f,-1e30f), alv));
    al = make_float4(fminf(fmaxf(alv.x, 0.f), 1.f), fminf(fmaxf(alv.y, 0.f), 1.f),
                     fminf(fmaxf(alv.z, 0.f), 1.f), fminf(fmaxf(alv.w, 0.f), 1.f));
    float4 mk = make_float4(ml.x > 0.5f ? 1.f : 0.f, ml.y > 0.5f ? 1.f : 0.f,
                            ml.z > 0.5f ? 1.f : 0.f, ml.w > 0.5f ? 1.f : 0.f);
    float4 g = f4mul(al, mk);
    float4 omg = make_float4(1.f - g.x, 1.f - g.y, 1.f - g.z, 1.f - g.w);

    float4 w3 = make_float4(omg.x * e0.x * einv.x / (s3v.x + kEps), omg.y * e0.y * einv.y / (s3v.y + kEps),
                            omg.z * e0.z * einv.z / (s3v.z + kEps), omg.w * e0.w * einv.w / (s3v.w + kEps));
    float4 w5 = make_float4(omg.x * e1.x * einv.x / (s5v.x + kEps), omg.y * e1.y * einv.y / (s5v.y + kEps),
                            omg.z * e1.z * einv.z / (s5v.z + kEps), omg.w * e1.w * einv.w / (s5v.w + kEps));
    float4 w7 = make_float4(omg.x * e2.x * einv.x / (s7v.x + kEps), omg.y * e2.y * einv.y / (s7v.y + kEps),
                            omg.z * e2.z * einv.z / (s7v.z + kEps), omg.w * e2.w * einv.w / (s7v.w + kEps));

    // Q = (w3*c3 + w5*c5 + w7*c7)*D0 + g*DL   (center Dt coef cancels)
    float4 cw = f4fma(w3, c3v, f4fma(w5, c5v, f4mul(w7, c7v)));
    float4 Q = f4fma(cw, d0, f4mul(g, dl));
    *(float4*)(&g_Q[p]) = Q;

    // ---- Pass 2: merge + store (re-loads are L2/L3 hits) ----
    int oi = 0;
#pragma unroll
    for (int i = 0; i < 49; ++i) {
        int dy = i / 7 - 3, dx = i % 7 - 3;
        if (dy == 0 && dx == 0) continue;
        float4 wv = f4mul(w7, ld4(a7p + (size_t)i * kHW));
        if (dy >= -2 && dy <= 2 && dx >= -2 && dx <= 2)
            wv = f4fma(w5, ld4(a5p + (size_t)((dy + 2) * 5 + (dx + 2)) * kHW), wv);
        if (dy >= -1 && dy <= 1 && dx >= -1 && dx <= 1)
            wv = f4fma(w3, ld4(a3p + (size_t)((dy + 1) * 3 + (dx + 1)) * kHW), wv);
        half4 h;
        h[0] = (half_t)wv.x; h[1] = (half_t)wv.y; h[2] = (half_t)wv.z; h[3] = (half_t)wv.w;
        *(half4*)(&g_Wh[(size_t)oi * kN + p]) = h;
        ++oi;
    }
}

// One propagation step, 4 pixels/thread (unchanged from round 4: ~12-13 us).
__global__ __launch_bounds__(kBlock) void step_kernel(
    const float* __restrict__ Din_ext, float* __restrict__ Dout_ext,
    int src_g, int dst_g)
{
    const float* Din = src_g ? g_ping : Din_ext;
    float* Dout = dst_g ? g_ping : Dout_ext;

    int t = blockIdx.x * kBlock + threadIdx.x;   // 0 .. kN/4-1
    int p = t * 4;
    int b = p / kHW;                             // kHW % 4 == 0
    int rem = p - b * kHW;
    int y = rem / kW;                            // kW % 4 == 0: stays in one row
    int x0 = rem - y * kW;
    const float* dinb = Din + (size_t)b * kHW;

    float4 q = *(const float4*)(&g_Q[p]);
    float acc[4] = {q.x, q.y, q.z, q.w};

    int oi = 0;
#pragma unroll
    for (int dy = -3; dy <= 3; ++dy) {
        int ny = y + dy;
        bool rv = (ny >= 0) && (ny < kH);
        if (!rv) { oi += (dy == 0) ? 6 : 7; continue; }   // zero contribution
        const float* dr = dinb + ny * kW;

        float rowv[12];   // covers x0-4 .. x0+7
#pragma unroll
        for (int s = 0; s < 3; ++s) {
            int xb = x0 + (s - 1) * 4;
            float4 v = (xb >= 0 && xb < kW) ? *(const float4*)(dr + xb)
                                            : make_float4(0.f, 0.f, 0.f, 0.f);
            rowv[s * 4 + 0] = v.x; rowv[s * 4 + 1] = v.y;
            rowv[s * 4 + 2] = v.z; rowv[s * 4 + 3] = v.w;
        }
#pragma unroll
        for (int dx = -3; dx <= 3; ++dx) {
            if (dy == 0 && dx == 0) continue;
            half4 w = *(const half4*)(&g_Wh[(size_t)oi * kN + p]);
#pragma unroll
            for (int j = 0; j < 4; ++j)
                acc[j] = fmaf((float)w[j], rowv[4 + j + dx], acc[j]);
            ++oi;
        }
    }

    float4 o;
    o.x = fminf(fmaxf(acc[0], 0.f), kDmax);
    o.y = fminf(fmaxf(acc[1], 0.f), kDmax);
    o.z = fminf(fmaxf(acc[2], 0.f), kDmax);
    o.w = fminf(fmaxf(acc[3], 0.f), kDmax);
    *(float4*)(&Dout[p]) = o;
}

extern "C" void kernel_launch(void* const* d_in, const int* in_sizes, int n_in,
                              void* d_out, int out_size, void* d_ws, size_t ws_size,
                              hipStream_t stream) {
    const float* D0 = (const float*)d_in[0];
    const float* DL = (const float*)d_in[1];
    const float* ML = (const float*)d_in[2];
    const float* A3 = (const float*)d_in[3];
    const float* A5 = (const float*)d_in[4];
    const float* A7 = (const float*)d_in[5];
    const float* SG = (const float*)d_in[6];
    const float* AL = (const float*)d_in[7];
    float* out = (float*)d_out;

    dim3 block(kBlock);
    dim3 gridQuarter(kN / 4 / kBlock);   // 836, exact

    prep_kernel<<<gridQuarter, block, 0, stream>>>(D0, DL, ML, A3, A5, A7, SG, AL);

    // Chain: D0 -> ping -> out -> ping -> out -> ping -> out
    step_kernel<<<gridQuarter, block, 0, stream>>>(D0, nullptr, 0, 1);
    step_kernel<<<gridQuarter, block, 0, stream>>>(nullptr, out, 1, 0);
    step_kernel<<<gridQuarter, block, 0, stream>>>(out, nullptr, 0, 1);
    step_kernel<<<gridQuarter, block, 0, stream>>>(nullptr, out, 1, 0);
    step_kernel<<<gridQuarter, block, 0, stream>>>(out, nullptr, 0, 1);
    step_kernel<<<gridQuarter, block, 0, stream>>>(nullptr, out, 1, 0);
}

// Round 8
// 256.700 us; speedup vs baseline: 1.4114x; 1.4114x over previous
//
#include <hip/hip_runtime.h>

namespace {
constexpr int kB = 2;
constexpr int kH = 352;
constexpr int kW = 1216;
constexpr int kHW = kH * kW;        // 428032
constexpr int kN = kB * kHW;        // 856064
constexpr float kDmax = 80.0f;
constexpr float kEps = 1e-6f;
constexpr int kBlock = 256;
constexpr int kPrepChunks = 4;      // sequential launches; chunk working set ~71+21 MB -> L3-resident for pass 2
constexpr int kPrepBlocksPerChunk = kN / 4 / kBlock / kPrepChunks;  // 209, exact
}

typedef _Float16 half_t;
typedef __attribute__((ext_vector_type(4))) _Float16 half4;

// Module-owned workspace, fully rewritten from inputs on every launch.
__device__ half_t g_Wh[(size_t)48 * kN];  // merged weights, fp16, ch-major (~82 MB)
__device__ float  g_Q[kN];                // fp32 constant term
__device__ float  g_ping[kN];             // Dt ping buffer

__device__ __forceinline__ float4 ld4(const float* p) { return *(const float4*)p; }
__device__ __forceinline__ float4 f4add(float4 a, float4 b) {
    return make_float4(a.x + b.x, a.y + b.y, a.z + b.z, a.w + b.w);
}
__device__ __forceinline__ float4 f4mul(float4 a, float4 b) {
    return make_float4(a.x * b.x, a.y * b.y, a.z * b.z, a.w * b.w);
}
__device__ __forceinline__ float4 f4fma(float4 a, float4 b, float4 c) {
    return make_float4(fmaf(a.x, b.x, c.x), fmaf(a.y, b.y, c.y),
                       fmaf(a.z, b.z, c.z), fmaf(a.w, b.w, c.w));
}
__device__ __forceinline__ float4 f4abs(float4 a) {
    return make_float4(fabsf(a.x), fabsf(a.y), fabsf(a.z), fabsf(a.w));
}
__device__ __forceinline__ float4 f4max(float4 a, float4 b) {
    return make_float4(fmaxf(a.x, b.x), fmaxf(a.y, b.y),
                       fmaxf(a.z, b.z), fmaxf(a.w, b.w));
}

// Merged-weight precompute, 4 pixels/thread, two passes, CHUNKED.
// R7 diagnosis: (a) buf[8] live set spilled to scratch (WRITE_SIZE 331 MB vs
// 86 produced, occ 19% at VGPR=128) -> buf[4], no min-waves hint; (b) pass-2
// reuse distance was the full 285 MB input (whole grid = one generation) ->
// L3 missed. Fix: 4 sequential chunk launches; each chunk's pass-1 footprint
// (~71 MB) is L3-resident when its pass 2 re-reads it.
__global__ __launch_bounds__(kBlock) void prep_kernel(
    const float* __restrict__ D0, const float* __restrict__ DL,
    const float* __restrict__ ML, const float* __restrict__ A3,
    const float* __restrict__ A5, const float* __restrict__ A7,
    const float* __restrict__ SG, const float* __restrict__ AL,
    int t0)
{
    int t = t0 + blockIdx.x * kBlock + threadIdx.x;
    int p = t * 4;
    int b = p / kHW;                             // kHW % 4 == 0
    int rem = p - b * kHW;

    const float* a3p = A3 + (size_t)b * 9 * kHW + rem;
    const float* a5p = A5 + (size_t)b * 25 * kHW + rem;
    const float* a7p = A7 + (size_t)b * 49 * kHW + rem;
    const float* sgp = SG + (size_t)b * 3 * kHW + rem;

    // ---- Pass 1: |.|-sums via 4-deep chunked float4 loads ----
    float4 zero = make_float4(0.f, 0.f, 0.f, 0.f);
    float4 s7v = zero, s5v = zero, s3v = zero;
    float4 c7v = zero, c5v = zero, c3v = zero;

#pragma unroll
    for (int ch = 0; ch < 12; ++ch) {            // a7: 48 of 49
        float4 buf[4];
#pragma unroll
        for (int j = 0; j < 4; ++j) buf[j] = ld4(a7p + (size_t)(ch * 4 + j) * kHW);
#pragma unroll
        for (int j = 0; j < 4; ++j) {
            if (ch * 4 + j == 24) c7v = buf[j];
            s7v = f4add(s7v, f4abs(buf[j]));
        }
    }
    s7v = f4add(s7v, f4abs(ld4(a7p + (size_t)48 * kHW)));

#pragma unroll
    for (int ch = 0; ch < 6; ++ch) {             // a5: 24 of 25
        float4 buf[4];
#pragma unroll
        for (int j = 0; j < 4; ++j) buf[j] = ld4(a5p + (size_t)(ch * 4 + j) * kHW);
#pragma unroll
        for (int j = 0; j < 4; ++j) {
            if (ch * 4 + j == 12) c5v = buf[j];
            s5v = f4add(s5v, f4abs(buf[j]));
        }
    }
    s5v = f4add(s5v, f4abs(ld4(a5p + (size_t)24 * kHW)));

#pragma unroll
    for (int ch = 0; ch < 2; ++ch) {             // a3: 8 of 9
        float4 buf[4];
#pragma unroll
        for (int j = 0; j < 4; ++j) buf[j] = ld4(a3p + (size_t)(ch * 4 + j) * kHW);
#pragma unroll
        for (int j = 0; j < 4; ++j) {
            if (ch * 4 + j == 4) c3v = buf[j];
            s3v = f4add(s3v, f4abs(buf[j]));
        }
    }
    s3v = f4add(s3v, f4abs(ld4(a3p + (size_t)8 * kHW)));

    // ---- Per-pixel scalars ----
    float4 g0 = ld4(sgp);
    float4 g1 = ld4(sgp + kHW);
    float4 g2 = ld4(sgp + 2 * kHW);
    float4 mx = f4max(g0, f4max(g1, g2));
    float4 e0 = make_float4(expf(g0.x - mx.x), expf(g0.y - mx.y), expf(g0.z - mx.z), expf(g0.w - mx.w));
    float4 e1 = make_float4(expf(g1.x - mx.x), expf(g1.y - mx.y), expf(g1.z - mx.z), expf(g1.w - mx.w));
    float4 e2 = make_float4(expf(g2.x - mx.x), expf(g2.y - mx.y), expf(g2.z - mx.z), expf(g2.w - mx.w));
    float4 einv = make_float4(1.f / (e0.x + e1.x + e2.x), 1.f / (e0.y + e1.y + e2.y),
                              1.f / (e0.z + e1.z + e2.z), 1.f / (e0.w + e1.w + e2.w));

    float4 alv = ld4(AL + p);
    float4 ml  = ld4(ML + p);
    float4 al = make_float4(fminf(fmaxf(alv.x, 0.f), 1.f), fminf(fmaxf(alv.y, 0.f), 1.f),
                            fminf(fmaxf(alv.z, 0.f), 1.f), fminf(fmaxf(alv.w, 0.f), 1.f));
    float4 mk = make_float4(ml.x > 0.5f ? 1.f : 0.f, ml.y > 0.5f ? 1.f : 0.f,
                            ml.z > 0.5f ? 1.f : 0.f, ml.w > 0.5f ? 1.f : 0.f);
    float4 g = f4mul(al, mk);
    float4 omg = make_float4(1.f - g.x, 1.f - g.y, 1.f - g.z, 1.f - g.w);

    float4 w3 = make_float4(omg.x * e0.x * einv.x / (s3v.x + kEps), omg.y * e0.y * einv.y / (s3v.y + kEps),
                            omg.z * e0.z * einv.z / (s3v.z + kEps), omg.w * e0.w * einv.w / (s3v.w + kEps));
    float4 w5 = make_float4(omg.x * e1.x * einv.x / (s5v.x + kEps), omg.y * e1.y * einv.y / (s5v.y + kEps),
                            omg.z * e1.z * einv.z / (s5v.z + kEps), omg.w * e1.w * einv.w / (s5v.w + kEps));
    float4 w7 = make_float4(omg.x * e2.x * einv.x / (s7v.x + kEps), omg.y * e2.y * einv.y / (s7v.y + kEps),
                            omg.z * e2.z * einv.z / (s7v.z + kEps), omg.w * e2.w * einv.w / (s7v.w + kEps));

    // Q = (w3*c3 + w5*c5 + w7*c7)*D0 + g*DL   (center Dt coef cancels)
    {
        float4 d0 = ld4(D0 + p);
        float4 dl = ld4(DL + p);
        float4 cw = f4fma(w3, c3v, f4fma(w5, c5v, f4mul(w7, c7v)));
        *(float4*)(&g_Q[p]) = f4fma(cw, d0, f4mul(g, dl));
    }

    // ---- Pass 2: merge + store (re-reads are chunk-local -> L3 hits) ----
    int oi = 0;
#pragma unroll
    for (int i = 0; i < 49; ++i) {
        int dy = i / 7 - 3, dx = i % 7 - 3;
        if (dy == 0 && dx == 0) continue;
        float4 wv = f4mul(w7, ld4(a7p + (size_t)i * kHW));
        if (dy >= -2 && dy <= 2 && dx >= -2 && dx <= 2)
            wv = f4fma(w5, ld4(a5p + (size_t)((dy + 2) * 5 + (dx + 2)) * kHW), wv);
        if (dy >= -1 && dy <= 1 && dx >= -1 && dx <= 1)
            wv = f4fma(w3, ld4(a3p + (size_t)((dy + 1) * 3 + (dx + 1)) * kHW), wv);
        half4 h;
        h[0] = (half_t)wv.x; h[1] = (half_t)wv.y; h[2] = (half_t)wv.z; h[3] = (half_t)wv.w;
        *(half4*)(&g_Wh[(size_t)oi * kN + p]) = h;
        ++oi;
    }
}

// One propagation step, 4 pixels/thread (unchanged from round 4: ~13.3 us).
__global__ __launch_bounds__(kBlock) void step_kernel(
    const float* __restrict__ Din_ext, float* __restrict__ Dout_ext,
    int src_g, int dst_g)
{
    const float* Din = src_g ? g_ping : Din_ext;
    float* Dout = dst_g ? g_ping : Dout_ext;

    int t = blockIdx.x * kBlock + threadIdx.x;   // 0 .. kN/4-1
    int p = t * 4;
    int b = p / kHW;                             // kHW % 4 == 0
    int rem = p - b * kHW;
    int y = rem / kW;                            // kW % 4 == 0: stays in one row
    int x0 = rem - y * kW;
    const float* dinb = Din + (size_t)b * kHW;

    float4 q = *(const float4*)(&g_Q[p]);
    float acc[4] = {q.x, q.y, q.z, q.w};

    int oi = 0;
#pragma unroll
    for (int dy = -3; dy <= 3; ++dy) {
        int ny = y + dy;
        bool rv = (ny >= 0) && (ny < kH);
        if (!rv) { oi += (dy == 0) ? 6 : 7; continue; }   // zero contribution
        const float* dr = dinb + ny * kW;

        float rowv[12];   // covers x0-4 .. x0+7
#pragma unroll
        for (int s = 0; s < 3; ++s) {
            int xb = x0 + (s - 1) * 4;
            float4 v = (xb >= 0 && xb < kW) ? *(const float4*)(dr + xb)
                                            : make_float4(0.f, 0.f, 0.f, 0.f);
            rowv[s * 4 + 0] = v.x; rowv[s * 4 + 1] = v.y;
            rowv[s * 4 + 2] = v.z; rowv[s * 4 + 3] = v.w;
        }
#pragma unroll
        for (int dx = -3; dx <= 3; ++dx) {
            if (dy == 0 && dx == 0) continue;
            half4 w = *(const half4*)(&g_Wh[(size_t)oi * kN + p]);
#pragma unroll
            for (int j = 0; j < 4; ++j)
                acc[j] = fmaf((float)w[j], rowv[4 + j + dx], acc[j]);
            ++oi;
        }
    }

    float4 o;
    o.x = fminf(fmaxf(acc[0], 0.f), kDmax);
    o.y = fminf(fmaxf(acc[1], 0.f), kDmax);
    o.z = fminf(fmaxf(acc[2], 0.f), kDmax);
    o.w = fminf(fmaxf(acc[3], 0.f), kDmax);
    *(float4*)(&Dout[p]) = o;
}

extern "C" void kernel_launch(void* const* d_in, const int* in_sizes, int n_in,
                              void* d_out, int out_size, void* d_ws, size_t ws_size,
                              hipStream_t stream) {
    const float* D0 = (const float*)d_in[0];
    const float* DL = (const float*)d_in[1];
    const float* ML = (const float*)d_in[2];
    const float* A3 = (const float*)d_in[3];
    const float* A5 = (const float*)d_in[4];
    const float* A7 = (const float*)d_in[5];
    const float* SG = (const float*)d_in[6];
    const float* AL = (const float*)d_in[7];
    float* out = (float*)d_out;

    dim3 block(kBlock);
    dim3 gridChunk(kPrepBlocksPerChunk);   // 209
    dim3 gridStep(kN / 4 / kBlock);        // 836, exact

    for (int c = 0; c < kPrepChunks; ++c)
        prep_kernel<<<gridChunk, block, 0, stream>>>(
            D0, DL, ML, A3, A5, A7, SG, AL, c * kPrepBlocksPerChunk * kBlock);

    // Chain: D0 -> ping -> out -> ping -> out -> ping -> out
    step_kernel<<<gridStep, block, 0, stream>>>(D0, nullptr, 0, 1);
    step_kernel<<<gridStep, block, 0, stream>>>(nullptr, out, 1, 0);
    step_kernel<<<gridStep, block, 0, stream>>>(out, nullptr, 0, 1);
    step_kernel<<<gridStep, block, 0, stream>>>(nullptr, out, 1, 0);
    step_kernel<<<gridStep, block, 0, stream>>>(out, nullptr, 0, 1);
    step_kernel<<<gridStep, block, 0, stream>>>(nullptr, out, 1, 0);
}

// Round 9
// 203.310 us; speedup vs baseline: 1.7821x; 1.2626x over previous
//
#include <hip/hip_runtime.h>

namespace {
constexpr int kB = 2;
constexpr int kH = 352;
constexpr int kW = 1216;
constexpr int kHW = kH * kW;        // 428032
constexpr int kN = kB * kHW;        // 856064
constexpr float kDmax = 80.0f;
constexpr float kEps = 1e-6f;
constexpr int kBlock = 256;
}

typedef _Float16 half_t;
typedef __attribute__((ext_vector_type(4))) _Float16 half4;

// Module-owned workspace, fully rewritten from inputs on every launch.
__device__ half_t g_Wh[(size_t)48 * kN];  // merged weights, fp16, ch-major (~82 MB)
__device__ float  g_Q[kN];                // fp32 constant term
__device__ float  g_ping[kN];             // Dt ping buffer

__device__ __forceinline__ float4 ld4(const float* p) { return *(const float4*)p; }
__device__ __forceinline__ float4 f4add(float4 a, float4 b) {
    return make_float4(a.x + b.x, a.y + b.y, a.z + b.z, a.w + b.w);
}
__device__ __forceinline__ float4 f4mul(float4 a, float4 b) {
    return make_float4(a.x * b.x, a.y * b.y, a.z * b.z, a.w * b.w);
}
__device__ __forceinline__ float4 f4fma(float4 a, float4 b, float4 c) {
    return make_float4(fmaf(a.x, b.x, c.x), fmaf(a.y, b.y, c.y),
                       fmaf(a.z, b.z, c.z), fmaf(a.w, b.w, c.w));
}
__device__ __forceinline__ float4 f4abs(float4 a) {
    return make_float4(fabsf(a.x), fabsf(a.y), fabsf(a.z), fabsf(a.w));
}
__device__ __forceinline__ float4 f4max(float4 a, float4 b) {
    return make_float4(fmaxf(a.x, b.x), fmaxf(a.y, b.y),
                       fmaxf(a.z, b.z), fmaxf(a.w, b.w));
}
__device__ __forceinline__ half4 toh4(float4 v) {
    half4 h;
    h[0] = (half_t)v.x; h[1] = (half_t)v.y; h[2] = (half_t)v.z; h[3] = (half_t)v.w;
    return h;
}
__device__ __forceinline__ float4 tof4(half4 h) {
    return make_float4((float)h[0], (float)h[1], (float)h[2], (float)h[3]);
}

// Merged-weight precompute: single read of all inputs.
// R8 lessons: fillBuffer streams 7.2 TB/s at 10% occupancy/8 VGPR -> wide
// back-to-back instructions are all that matters; chunked small grids starve
// the device. Here: 4 px/thread float4 loads, 8-deep batches (64 KB/CU in
// flight); a7+a5 stashed fp16 in LDS (148 KB, per-thread-private slots, NO
// barriers -> waves drift, phases overlap); a3 in 36 VGPRs. Merge re-reads
// LDS (8 B/lane, 2-way bank alias = free) instead of HBM -> no second read.
__global__ __launch_bounds__(kBlock, 2) void prep_kernel(
    const float* __restrict__ D0, const float* __restrict__ DL,
    const float* __restrict__ ML, const float* __restrict__ A3,
    const float* __restrict__ A5, const float* __restrict__ A7,
    const float* __restrict__ SG, const float* __restrict__ AL)
{
    __shared__ half_t sh7[49 * kBlock * 4];   // 100352 B
    __shared__ half_t sh5[25 * kBlock * 4];   //  51200 B  (total 148 KiB)

    int tid = threadIdx.x;
    int t = blockIdx.x * kBlock + tid;        // 0 .. kN/4-1
    int p = t * 4;
    int b = p / kHW;                          // kHW % 1024 == 0: block batch-uniform
    int rem = p - b * kHW;
    int sb = tid * 4;                         // this thread's LDS pixel base

    const float* a3p = A3 + (size_t)b * 9 * kHW + rem;
    const float* a5p = A5 + (size_t)b * 25 * kHW + rem;
    const float* a7p = A7 + (size_t)b * 49 * kHW + rem;
    const float* sgp = SG + (size_t)b * 3 * kHW + rem;

    float4 zero = make_float4(0.f, 0.f, 0.f, 0.f);

    // ---- Stream a7: 6x8 batches + 1; abs-sum, stash fp16 ----
    float4 s7v = zero, c7v = zero;
#pragma unroll
    for (int ch = 0; ch < 6; ++ch) {
        float4 buf[8];
#pragma unroll
        for (int j = 0; j < 8; ++j) buf[j] = ld4(a7p + (size_t)(ch * 8 + j) * kHW);
#pragma unroll
        for (int j = 0; j < 8; ++j) {
            int c = ch * 8 + j;
            if (c == 24) c7v = buf[j];
            s7v = f4add(s7v, f4abs(buf[j]));
            *(half4*)(&sh7[c * (kBlock * 4) + sb]) = toh4(buf[j]);
        }
    }
    {
        float4 l = ld4(a7p + (size_t)48 * kHW);
        s7v = f4add(s7v, f4abs(l));
        *(half4*)(&sh7[48 * (kBlock * 4) + sb]) = toh4(l);
    }

    // ---- Stream a5: 3x8 batches + 1 ----
    float4 s5v = zero, c5v = zero;
#pragma unroll
    for (int ch = 0; ch < 3; ++ch) {
        float4 buf[8];
#pragma unroll
        for (int j = 0; j < 8; ++j) buf[j] = ld4(a5p + (size_t)(ch * 8 + j) * kHW);
#pragma unroll
        for (int j = 0; j < 8; ++j) {
            int c = ch * 8 + j;
            if (c == 12) c5v = buf[j];
            s5v = f4add(s5v, f4abs(buf[j]));
            *(half4*)(&sh5[c * (kBlock * 4) + sb]) = toh4(buf[j]);
        }
    }
    {
        float4 l = ld4(a5p + (size_t)24 * kHW);
        s5v = f4add(s5v, f4abs(l));
        *(half4*)(&sh5[24 * (kBlock * 4) + sb]) = toh4(l);
    }

    // ---- a3 stays in registers (9 float4 = 36 VGPR) ----
    float4 a3r[9];
    float4 s3v = zero;
#pragma unroll
    for (int c = 0; c < 9; ++c) a3r[c] = ld4(a3p + (size_t)c * kHW);
#pragma unroll
    for (int c = 0; c < 9; ++c) s3v = f4add(s3v, f4abs(a3r[c]));

    // ---- Per-pixel scalars ----
    float4 g0 = ld4(sgp);
    float4 g1 = ld4(sgp + kHW);
    float4 g2 = ld4(sgp + 2 * kHW);
    float4 mx = f4max(g0, f4max(g1, g2));
    float4 e0 = make_float4(expf(g0.x - mx.x), expf(g0.y - mx.y), expf(g0.z - mx.z), expf(g0.w - mx.w));
    float4 e1 = make_float4(expf(g1.x - mx.x), expf(g1.y - mx.y), expf(g1.z - mx.z), expf(g1.w - mx.w));
    float4 e2 = make_float4(expf(g2.x - mx.x), expf(g2.y - mx.y), expf(g2.z - mx.z), expf(g2.w - mx.w));
    float4 einv = make_float4(1.f / (e0.x + e1.x + e2.x), 1.f / (e0.y + e1.y + e2.y),
                              1.f / (e0.z + e1.z + e2.z), 1.f / (e0.w + e1.w + e2.w));

    float4 alv = ld4(AL + p);
    float4 ml  = ld4(ML + p);
    float4 al = make_float4(fminf(fmaxf(alv.x, 0.f), 1.f), fminf(fmaxf(alv.y, 0.f), 1.f),
                            fminf(fmaxf(alv.z, 0.f), 1.f), fminf(fmaxf(alv.w, 0.f), 1.f));
    float4 mk = make_float4(ml.x > 0.5f ? 1.f : 0.f, ml.y > 0.5f ? 1.f : 0.f,
                            ml.z > 0.5f ? 1.f : 0.f, ml.w > 0.5f ? 1.f : 0.f);
    float4 g = f4mul(al, mk);
    float4 omg = make_float4(1.f - g.x, 1.f - g.y, 1.f - g.z, 1.f - g.w);

    float4 w3 = make_float4(omg.x * e0.x * einv.x / (s3v.x + kEps), omg.y * e0.y * einv.y / (s3v.y + kEps),
                            omg.z * e0.z * einv.z / (s3v.z + kEps), omg.w * e0.w * einv.w / (s3v.w + kEps));
    float4 w5 = make_float4(omg.x * e1.x * einv.x / (s5v.x + kEps), omg.y * e1.y * einv.y / (s5v.y + kEps),
                            omg.z * e1.z * einv.z / (s5v.z + kEps), omg.w * e1.w * einv.w / (s5v.w + kEps));
    float4 w7 = make_float4(omg.x * e2.x * einv.x / (s7v.x + kEps), omg.y * e2.y * einv.y / (s7v.y + kEps),
                            omg.z * e2.z * einv.z / (s7v.z + kEps), omg.w * e2.w * einv.w / (s7v.w + kEps));

    // Q = (w3*c3 + w5*c5 + w7*c7)*D0 + g*DL   (center Dt coef cancels)
    {
        float4 d0 = ld4(D0 + p);
        float4 dl = ld4(DL + p);
        float4 cw = f4fma(w3, a3r[4], f4fma(w5, c5v, f4mul(w7, c7v)));
        *(float4*)(&g_Q[p]) = f4fma(cw, d0, f4mul(g, dl));
    }

    // ---- Merge from LDS (own slots; no barrier needed) + store fp16 ----
    int oi = 0;
#pragma unroll
    for (int i = 0; i < 49; ++i) {
        int dy = i / 7 - 3, dx = i % 7 - 3;
        if (dy == 0 && dx == 0) continue;
        float4 a7v = tof4(*(const half4*)(&sh7[i * (kBlock * 4) + sb]));
        float4 wv = f4mul(w7, a7v);
        if (dy >= -2 && dy <= 2 && dx >= -2 && dx <= 2) {
            float4 a5v = tof4(*(const half4*)(&sh5[((dy + 2) * 5 + (dx + 2)) * (kBlock * 4) + sb]));
            wv = f4fma(w5, a5v, wv);
        }
        if (dy >= -1 && dy <= 1 && dx >= -1 && dx <= 1)
            wv = f4fma(w3, a3r[(dy + 1) * 3 + (dx + 1)], wv);
        *(half4*)(&g_Wh[(size_t)oi * kN + p]) = toh4(wv);
        ++oi;
    }
}

// One propagation step, 4 pixels/thread (unchanged from round 4: ~13.3 us).
__global__ __launch_bounds__(kBlock) void step_kernel(
    const float* __restrict__ Din_ext, float* __restrict__ Dout_ext,
    int src_g, int dst_g)
{
    const float* Din = src_g ? g_ping : Din_ext;
    float* Dout = dst_g ? g_ping : Dout_ext;

    int t = blockIdx.x * kBlock + threadIdx.x;   // 0 .. kN/4-1
    int p = t * 4;
    int b = p / kHW;                             // kHW % 4 == 0
    int rem = p - b * kHW;
    int y = rem / kW;                            // kW % 4 == 0: stays in one row
    int x0 = rem - y * kW;
    const float* dinb = Din + (size_t)b * kHW;

    float4 q = *(const float4*)(&g_Q[p]);
    float acc[4] = {q.x, q.y, q.z, q.w};

    int oi = 0;
#pragma unroll
    for (int dy = -3; dy <= 3; ++dy) {
        int ny = y + dy;
        bool rv = (ny >= 0) && (ny < kH);
        if (!rv) { oi += (dy == 0) ? 6 : 7; continue; }   // zero contribution
        const float* dr = dinb + ny * kW;

        float rowv[12];   // covers x0-4 .. x0+7
#pragma unroll
        for (int s = 0; s < 3; ++s) {
            int xb = x0 + (s - 1) * 4;
            float4 v = (xb >= 0 && xb < kW) ? *(const float4*)(dr + xb)
                                            : make_float4(0.f, 0.f, 0.f, 0.f);
            rowv[s * 4 + 0] = v.x; rowv[s * 4 + 1] = v.y;
            rowv[s * 4 + 2] = v.z; rowv[s * 4 + 3] = v.w;
        }
#pragma unroll
        for (int dx = -3; dx <= 3; ++dx) {
            if (dy == 0 && dx == 0) continue;
            half4 w = *(const half4*)(&g_Wh[(size_t)oi * kN + p]);
#pragma unroll
            for (int j = 0; j < 4; ++j)
                acc[j] = fmaf((float)w[j], rowv[4 + j + dx], acc[j]);
            ++oi;
        }
    }

    float4 o;
    o.x = fminf(fmaxf(acc[0], 0.f), kDmax);
    o.y = fminf(fmaxf(acc[1], 0.f), kDmax);
    o.z = fminf(fmaxf(acc[2], 0.f), kDmax);
    o.w = fminf(fmaxf(acc[3], 0.f), kDmax);
    *(float4*)(&Dout[p]) = o;
}

extern "C" void kernel_launch(void* const* d_in, const int* in_sizes, int n_in,
                              void* d_out, int out_size, void* d_ws, size_t ws_size,
                              hipStream_t stream) {
    const float* D0 = (const float*)d_in[0];
    const float* DL = (const float*)d_in[1];
    const float* ML = (const float*)d_in[2];
    const float* A3 = (const float*)d_in[3];
    const float* A5 = (const float*)d_in[4];
    const float* A7 = (const float*)d_in[5];
    const float* SG = (const float*)d_in[6];
    const float* AL = (const float*)d_in[7];
    float* out = (float*)d_out;

    dim3 block(kBlock);
    dim3 grid(kN / 4 / kBlock);   // 836, exact

    prep_kernel<<<grid, block, 0, stream>>>(D0, DL, ML, A3, A5, A7, SG, AL);

    // Chain: D0 -> ping -> out -> ping -> out -> ping -> out
    step_kernel<<<grid, block, 0, stream>>>(D0, nullptr, 0, 1);
    step_kernel<<<grid, block, 0, stream>>>(nullptr, out, 1, 0);
    step_kernel<<<grid, block, 0, stream>>>(out, nullptr, 0, 1);
    step_kernel<<<grid, block, 0, stream>>>(nullptr, out, 1, 0);
    step_kernel<<<grid, block, 0, stream>>>(out, nullptr, 0, 1);
    step_kernel<<<grid, block, 0, stream>>>(nullptr, out, 1, 0);
}